// Round 6
// baseline (150.434 us; speedup 1.0000x reference)
//
#include <hip/hip_runtime.h>

#define B_  4
#define N_  4096
#define K_  32
#define C_  64
#define DH_ 128
#define PPB 16

typedef _Float16 half2v __attribute__((ext_vector_type(2)));
typedef _Float16 half8  __attribute__((ext_vector_type(8)));
typedef __fp16   fp16x2 __attribute__((ext_vector_type(2)));
typedef float  floatx16 __attribute__((ext_vector_type(16)));
typedef unsigned int uint_t;

union HU { half2v h; uint_t u; };
union HU2 { fp16x2 h; uint_t u; };

__device__ __forceinline__ uint_t pk2(float a, float b) {
    HU2 x; x.h = __builtin_amdgcn_cvt_pkrtz(a, b);   // v_cvt_pkrtz_f16_f32
    return x.u;
}

// ---------------------------------------------------------------------------
// Kernel 0: xyz copy (output 0) + Bpack = (W_h * s_h) as f16 in MFMA B-frag
// order: flat = ((ob*8+c)*64+l)*8+j -> W_h[o=ob*32+(l&31)][i=c*16+(l>>5)*8+j].
// 49152 + 16384 = 65536 = 256*256.
// ---------------------------------------------------------------------------
__global__ __launch_bounds__(256) void k_transforms(
    const float* __restrict__ xyz,
    const float* __restrict__ W_h,
    const float* __restrict__ s_h,
    float* __restrict__ out_xyz,
    _Float16* __restrict__ Bpack)
{
    int e = blockIdx.x * 256 + threadIdx.x;
    if (e < B_*N_*3) { out_xyz[e] = xyz[e]; return; }
    e -= B_*N_*3;
    int j = e & 7, l = (e >> 3) & 63, c = (e >> 9) & 7, ob = e >> 12;
    int o = ob*32 + (l & 31);
    int i = c*16 + (l >> 5)*8 + j;
    Bpack[e] = (_Float16)(W_h[o*DH_ + i] * s_h[o]);
}

// ---------------------------------------------------------------------------
// Kernel 1: per-point precompute, 16-pt tiles (1024 blocks, 4/CU).
//  Pgv[n][o] = feats[n]·W_gv^T  (16x64x64 GEMM, both operands LDS-staged)
//  QsH [n] (f16x2 words 0..31 gu | 32..63 gv): center half, affine folded
//  PcatH[n] (same layout): neighbor half, scale folded
//  => fuse[k][i] = relu(QsH[n][i] + PcatH[idx[n][k]][i])  in f16
// ---------------------------------------------------------------------------
__global__ __launch_bounds__(256) void k_pre(
    const float* __restrict__ xyz,
    const float* __restrict__ features,
    const float* __restrict__ W_gv,
    const float* __restrict__ W_gu,
    const float* __restrict__ s_gu, const float* __restrict__ b_gu,
    const float* __restrict__ s_gv, const float* __restrict__ b_gv,
    uint_t* __restrict__ QsH,
    uint_t* __restrict__ PcatH)
{
    const int b  = blockIdx.x >> 8;
    const int n0 = (blockIdx.x & 255) * 16;
    const int t  = threadIdx.x;

    __shared__ __align__(16) float ftile[64 * 17];   // [c][n], stride 17
    __shared__ __align__(16) float wtile[64 * 68];   // [c][o], stride 68

    {   // stage features tile: 1 float4/thread (64c x 16n)
        const int c = t >> 2, nq = t & 3;
        float4 f4 = *(const float4*)&features[(b*C_ + c)*N_ + n0 + nq*4];
        ftile[c*17 + nq*4 + 0] = f4.x;
        ftile[c*17 + nq*4 + 1] = f4.y;
        ftile[c*17 + nq*4 + 2] = f4.z;
        ftile[c*17 + nq*4 + 3] = f4.w;
    }
    for (int e = t; e < 64*64; e += 256) {   // stage W_gv transposed
        int o = e >> 6, c = e & 63;
        wtile[c*68 + o] = W_gv[e];
    }
    __syncthreads();

    const int n  = t >> 4;       // 0..15
    const int oq = t & 15;       // o-chunk of 4
    const int o0 = oq * 4;

    float acc[4] = {};
    for (int c = 0; c < 64; c++) {
        const float a = ftile[c*17 + n];            // 16-lane broadcast
        const float4 wv = *(const float4*)&wtile[c*68 + o0];
        acc[0] = fmaf(a, wv.x, acc[0]);
        acc[1] = fmaf(a, wv.y, acc[1]);
        acc[2] = fmaf(a, wv.z, acc[2]);
        acc[3] = fmaf(a, wv.w, acc[3]);
    }

    const int bn = b*N_ + n0 + n;
    const float x0 = xyz[bn*3+0], x1 = xyz[bn*3+1], x2 = xyz[bn*3+2];

    const float4 sgu = *(const float4*)&s_gu[o0];
    const float4 bgu = *(const float4*)&b_gu[o0];
    const float4 sgv = *(const float4*)&s_gv[o0];
    const float4 bgv = *(const float4*)&b_gv[o0];

    float q[4], r[4];
#pragma unroll
    for (int jj = 0; jj < 4; jj++) {
        const int o = o0 + jj;
        q[jj] = x0*W_gu[o*6+0] + x1*W_gu[o*6+1] + x2*W_gu[o*6+2];
        r[jj] = x0*W_gu[o*6+3] + x1*W_gu[o*6+4] + x2*W_gu[o*6+5];
    }
    uint2 qa, pa;
    // gu half (words 0..31)
    qa.x = pk2(q[0]*sgu.x+bgu.x, q[1]*sgu.y+bgu.y);
    qa.y = pk2(q[2]*sgu.z+bgu.z, q[3]*sgu.w+bgu.w);
    pa.x = pk2(r[0]*sgu.x, r[1]*sgu.y);
    pa.y = pk2(r[2]*sgu.z, r[3]*sgu.w);
    *(uint2*)&QsH  [bn*64 + oq*2] = qa;
    *(uint2*)&PcatH[bn*64 + oq*2] = pa;
    // gv half (words 32..63)
    qa.x = pk2(acc[0]*sgv.x+bgv.x, acc[1]*sgv.y+bgv.y);
    qa.y = pk2(acc[2]*sgv.z+bgv.z, acc[3]*sgv.w+bgv.w);
    pa.x = pk2(acc[0]*sgv.x, acc[1]*sgv.y);
    pa.y = pk2(acc[2]*sgv.z, acc[3]*sgv.w);
    *(uint2*)&QsH  [bn*64 + 32 + oq*2] = qa;
    *(uint2*)&PcatH[bn*64 + 32 + oq*2] = pa;
}

// ---------------------------------------------------------------------------
// Kernel 2: fused main + f-layer, barrier-free main loop.
//  Wave-pair (slot=w>>1) owns a point stream; wave handles o-half oh=w&1.
//  A-fragments built DIRECTLY in registers: lane l (m=l&31, hh=l>>5) owns
//  neighbor j=idx[n][m]; per c-chunk it gathers uint4 = PcatH[(b*N+j)*64 +
//  c*8+hh*4], adds broadcast QsH[n] words, pk-relu -> exactly the
//  mfma_f32_32x32x16_f16 A-layout A[m=lane&31][k=(lane>>5)*8+j]. No fuse LDS,
//  no ds traffic, no barriers until the f-layer phase.
// ---------------------------------------------------------------------------
__global__ __launch_bounds__(256) void k_main(
    const int*      __restrict__ idx,
    const uint_t*   __restrict__ QsH,
    const uint_t*   __restrict__ PcatH,
    const _Float16* __restrict__ Bpack,
    const float*    __restrict__ b_h,
    const float*    __restrict__ W_f,
    const float*    __restrict__ s_f, const float* __restrict__ b_f,
    const float*    __restrict__ features,
    float* __restrict__ outF)
{
    const int t    = threadIdx.x;
    const int w    = t >> 6;
    const int lane = t & 63;
    const int m    = lane & 31;
    const int hh   = lane >> 5;
    const int slot = w >> 1;     // point-stream
    const int oh   = w & 1;      // o-half

    __shared__ __align__(16) float pooledAll[PPB * 136];

    half8 Bf[2][8];
#pragma unroll
    for (int ob = 0; ob < 2; ob++)
#pragma unroll
        for (int c = 0; c < 8; c++)
            Bf[ob][c] = *(const half8*)&Bpack[(((oh*2 + ob)*8 + c)*64 + lane)*8];

    const float bh0 = b_h[(oh*2+0)*32 + m];
    const float bh1 = b_h[(oh*2+1)*32 + m];

    const int bnb   = blockIdx.x * PPB;
    const int base0 = bnb & ~(N_ - 1);           // b*N_
    const half2v zero2 = {(_Float16)0.f, (_Float16)0.f};

    for (int pp = slot; pp < PPB; pp += 2) {
        const int bn = bnb + pp;
        const int n  = bn & (N_ - 1);
        const int j  = idx[n*K_ + m];            // lane's neighbor row
        const uint_t* Pb = PcatH + (size_t)(base0 + j)*64 + hh*4;
        const uint_t* Qb = QsH   + (size_t)bn*64 + hh*4;

        floatx16 acc0 = {}, acc1 = {};
#pragma unroll
        for (int c = 0; c < 8; c++) {
            const uint4 p4 = *(const uint4*)(Pb + c*8);
            const uint4 q4 = *(const uint4*)(Qb + c*8);
            union { uint_t u[4]; half8 h; } av;
#pragma unroll
            for (int qq = 0; qq < 4; qq++) {
                HU a, p;
                a.u = (&q4.x)[qq]; p.u = (&p4.x)[qq];
                half2v v = a.h + p.h;                        // v_pk_add_f16
                v = __builtin_elementwise_max(v, zero2);     // v_pk_max_f16
                HU o2; o2.h = v;
                av.u[qq] = o2.u;
            }
            acc0 = __builtin_amdgcn_mfma_f32_32x32x16_f16(av.h, Bf[0][c], acc0, 0, 0, 0);
            acc1 = __builtin_amdgcn_mfma_f32_32x32x16_f16(av.h, Bf[1][c], acc1, 0, 0, 0);
        }

        float v0 = 0.f, v1 = 0.f;
#pragma unroll
        for (int rg = 0; rg < 16; rg++) {
            v0 += fmaxf(acc0[rg] + bh0, 0.f);
            v1 += fmaxf(acc1[rg] + bh1, 0.f);
        }
        v0 += __shfl_xor(v0, 32);
        v1 += __shfl_xor(v1, 32);
        if (hh == 0) {
            pooledAll[pp*136 + (oh*2+0)*32 + m] = v0;
            pooledAll[pp*136 + (oh*2+1)*32 + m] = v1;
        }
    }
    __syncthreads();

    // ---- f layer + residual for the block's 16 points ----
    const int b  = bnb >> 12;
    const int n0 = bnb & (N_ - 1);
    const int c  = t >> 2;       // 0..63
    const int nq = t & 3;        // 4 n's per thread

    float acc[4] = {};
    for (int i0 = 0; i0 < DH_; i0 += 4) {
        const float4 wv = *(const float4*)&W_f[c*DH_ + i0];
#pragma unroll
        for (int r = 0; r < 4; r++) {
            const float4 p = *(const float4*)&pooledAll[(nq*4 + r)*136 + i0];
            acc[r] += wv.x*p.x + wv.y*p.y + wv.z*p.z + wv.w*p.w;
        }
    }
    const float sfc = s_f[c] * (1.f/(float)K_);
    const float bfc = b_f[c];
    const float4 fr = *(const float4*)&features[(b*C_ + c)*N_ + n0 + nq*4];
    float4 ov;
    ov.x = fmaxf(acc[0]*sfc + bfc, 0.f) + fr.x;
    ov.y = fmaxf(acc[1]*sfc + bfc, 0.f) + fr.y;
    ov.z = fmaxf(acc[2]*sfc + bfc, 0.f) + fr.z;
    ov.w = fmaxf(acc[3]*sfc + bfc, 0.f) + fr.w;
    *(float4*)&outF[(b*C_ + c)*N_ + n0 + nq*4] = ov;
}

// ---------------------------------------------------------------------------
extern "C" void kernel_launch(void* const* d_in, const int* in_sizes, int n_in,
                              void* d_out, int out_size, void* d_ws, size_t ws_size,
                              hipStream_t stream)
{
    const float* xyz      = (const float*)d_in[0];
    const float* features = (const float*)d_in[1];
    const int*   idx      = (const int*)  d_in[2];
    const float* W_gu     = (const float*)d_in[3];
    const float* s_gu     = (const float*)d_in[4];
    const float* b_gu     = (const float*)d_in[5];
    const float* W_gv     = (const float*)d_in[6];
    const float* s_gv     = (const float*)d_in[7];
    const float* b_gv     = (const float*)d_in[8];
    const float* W_h      = (const float*)d_in[9];
    const float* s_h      = (const float*)d_in[10];
    const float* b_h      = (const float*)d_in[11];
    const float* W_f      = (const float*)d_in[12];
    const float* s_f      = (const float*)d_in[13];
    const float* b_f      = (const float*)d_in[14];

    float* out  = (float*)d_out;          // tuple: xyz first, then out
    float* outF = out + B_*N_*3;

    // workspace carve (~8.1 MB)
    char* wp = (char*)d_ws;
    uint_t*   QsH   = (uint_t*)wp;   wp += (size_t)B_*N_*64*4;    // 4 MB
    uint_t*   PcatH = (uint_t*)wp;   wp += (size_t)B_*N_*64*4;    // 4 MB
    _Float16* Bpack = (_Float16*)wp; wp += DH_*DH_*2;             // 32 KB

    k_transforms<<<256, 256, 0, stream>>>(xyz, W_h, s_h, out, Bpack);
    k_pre<<<B_*(N_/16), 256, 0, stream>>>(xyz, features, W_gv, W_gu,
                                          s_gu, b_gu, s_gv, b_gv, QsH, PcatH);
    k_main<<<(B_*N_)/PPB, 256, 0, stream>>>(idx, QsH, PcatH, Bpack, b_h,
                                            W_f, s_f, b_f, features, outF);
}

// Round 7
// 130.442 us; speedup vs baseline: 1.1533x; 1.1533x over previous
//
#include <hip/hip_runtime.h>

#define B_  4
#define N_  4096
#define K_  32
#define C_  64
#define DH_ 128
#define PPB 16

typedef _Float16 half2v __attribute__((ext_vector_type(2)));
typedef _Float16 half8  __attribute__((ext_vector_type(8)));
typedef __fp16   fp16x2 __attribute__((ext_vector_type(2)));
typedef float  floatx16 __attribute__((ext_vector_type(16)));
typedef unsigned int uint_t;

union HU { half2v h; uint_t u; };
union HU2 { fp16x2 h; uint_t u; };

__device__ __forceinline__ uint_t pk2(float a, float b) {
    HU2 x; x.h = __builtin_amdgcn_cvt_pkrtz(a, b);   // v_cvt_pkrtz_f16_f32
    return x.u;
}

// ---------------------------------------------------------------------------
// Kernel 1 (merged prep): 512 blocks x 256 thr; block = (b = blk>>7, 32-pt tile).
//  Side jobs spread across blocks: xyz copy (512*96) + Bpack (512*32).
//  Main job: Pgv = feats·W_gv^T (32n x 64o x 64c, LDS-staged), then
//   QsH [n] f16x2 (words 0..31 gu-center | 32..63 gv-center), affine folded
//   PcatH[n] f16x2 (neighbor halves), scale folded
//  => fuse[k][i] = relu(QsH[n][i] + PcatH[idx[n][k]][i])
// ---------------------------------------------------------------------------
__global__ __launch_bounds__(256) void k_prep(
    const float* __restrict__ xyz,
    const float* __restrict__ features,
    const float* __restrict__ W_gv,
    const float* __restrict__ W_gu,
    const float* __restrict__ s_gu, const float* __restrict__ b_gu,
    const float* __restrict__ s_gv, const float* __restrict__ b_gv,
    const float* __restrict__ W_h,  const float* __restrict__ s_h,
    float* __restrict__ out_xyz,
    _Float16* __restrict__ Bpack,
    uint_t* __restrict__ QsH,
    uint_t* __restrict__ PcatH)
{
    const int blk = blockIdx.x;
    const int b   = blk >> 7;
    const int n0  = (blk & 127) * 32;
    const int t   = threadIdx.x;

    // side job A: xyz copy (output 0 of the tuple). 512*96 = 49152.
    if (t < 96) { int e = blk*96 + t; out_xyz[e] = xyz[e]; }
    // side job B: Bpack = (W_h * s_h) f16, MFMA B-frag order. 512*32 = 16384.
    {
        int e = blk*32 + t;
        if (t < 32) {
            int j = e & 7, l = (e >> 3) & 63, c = (e >> 9) & 7, ob = e >> 12;
            int o = ob*32 + (l & 31);
            int i = c*16 + (l >> 5)*8 + j;
            Bpack[e] = (_Float16)(W_h[o*DH_ + i] * s_h[o]);
        }
    }

    __shared__ __align__(16) float ftile[64 * 33];   // [c][n], stride 33
    __shared__ __align__(16) float wtile[64 * 68];   // [c][o], stride 68

#pragma unroll
    for (int r = 0; r < 2; r++) {    // features tile: 64c x 32n
        const int i4 = r*256 + t, c = i4 >> 3, nq = i4 & 7;
        const float4 f4 = *(const float4*)&features[(b*C_ + c)*N_ + n0 + nq*4];
        ftile[c*33 + nq*4 + 0] = f4.x;
        ftile[c*33 + nq*4 + 1] = f4.y;
        ftile[c*33 + nq*4 + 2] = f4.z;
        ftile[c*33 + nq*4 + 3] = f4.w;
    }
#pragma unroll
    for (int r = 0; r < 4; r++) {    // W_gv transposed: [c][o]
        const int e4 = r*256 + t, o = e4 >> 4, c0 = (e4 & 15)*4;
        const float4 w4 = *(const float4*)&W_gv[o*C_ + c0];
        wtile[(c0+0)*68 + o] = w4.x;
        wtile[(c0+1)*68 + o] = w4.y;
        wtile[(c0+2)*68 + o] = w4.z;
        wtile[(c0+3)*68 + o] = w4.w;
    }
    __syncthreads();

    const int n  = t >> 3;       // 0..31
    const int og = t & 7;        // o-chunk of 8
    const int o0 = og * 8;

    float acc[8] = {};
    for (int c = 0; c < 64; c++) {
        const float a = ftile[c*33 + n];            // 8-lane broadcast
        float wv[8];
        *(float4*)&wv[0] = *(const float4*)&wtile[c*68 + o0];
        *(float4*)&wv[4] = *(const float4*)&wtile[c*68 + o0 + 4];
#pragma unroll
        for (int oo = 0; oo < 8; oo++)
            acc[oo] = fmaf(a, wv[oo], acc[oo]);
    }

    const int bn = b*N_ + n0 + n;
    const float x0 = xyz[bn*3+0], x1 = xyz[bn*3+1], x2 = xyz[bn*3+2];

    float sgu[8], bgu[8], sgv[8], bgv[8];
    *(float4*)&sgu[0] = *(const float4*)&s_gu[o0]; *(float4*)&sgu[4] = *(const float4*)&s_gu[o0+4];
    *(float4*)&bgu[0] = *(const float4*)&b_gu[o0]; *(float4*)&bgu[4] = *(const float4*)&b_gu[o0+4];
    *(float4*)&sgv[0] = *(const float4*)&s_gv[o0]; *(float4*)&sgv[4] = *(const float4*)&s_gv[o0+4];
    *(float4*)&bgv[0] = *(const float4*)&b_gv[o0]; *(float4*)&bgv[4] = *(const float4*)&b_gv[o0+4];

    float qv[8], rv[8];
#pragma unroll
    for (int oo = 0; oo < 8; oo++) {
        const int o = o0 + oo;
        qv[oo] = x0*W_gu[o*6+0] + x1*W_gu[o*6+1] + x2*W_gu[o*6+2];
        rv[oo] = x0*W_gu[o*6+3] + x1*W_gu[o*6+4] + x2*W_gu[o*6+5];
    }
    uint4 qa, pa;
    // gu half (words 0..31)
    qa.x = pk2(qv[0]*sgu[0]+bgu[0], qv[1]*sgu[1]+bgu[1]);
    qa.y = pk2(qv[2]*sgu[2]+bgu[2], qv[3]*sgu[3]+bgu[3]);
    qa.z = pk2(qv[4]*sgu[4]+bgu[4], qv[5]*sgu[5]+bgu[5]);
    qa.w = pk2(qv[6]*sgu[6]+bgu[6], qv[7]*sgu[7]+bgu[7]);
    pa.x = pk2(rv[0]*sgu[0], rv[1]*sgu[1]);
    pa.y = pk2(rv[2]*sgu[2], rv[3]*sgu[3]);
    pa.z = pk2(rv[4]*sgu[4], rv[5]*sgu[5]);
    pa.w = pk2(rv[6]*sgu[6], rv[7]*sgu[7]);
    *(uint4*)&QsH  [bn*64 + og*4] = qa;
    *(uint4*)&PcatH[bn*64 + og*4] = pa;
    // gv half (words 32..63)
    qa.x = pk2(acc[0]*sgv[0]+bgv[0], acc[1]*sgv[1]+bgv[1]);
    qa.y = pk2(acc[2]*sgv[2]+bgv[2], acc[3]*sgv[3]+bgv[3]);
    qa.z = pk2(acc[4]*sgv[4]+bgv[4], acc[5]*sgv[5]+bgv[5]);
    qa.w = pk2(acc[6]*sgv[6]+bgv[6], acc[7]*sgv[7]+bgv[7]);
    pa.x = pk2(acc[0]*sgv[0], acc[1]*sgv[1]);
    pa.y = pk2(acc[2]*sgv[2], acc[3]*sgv[3]);
    pa.z = pk2(acc[4]*sgv[4], acc[5]*sgv[5]);
    pa.w = pk2(acc[6]*sgv[6], acc[7]*sgv[7]);
    *(uint4*)&QsH  [bn*64 + 32 + og*4] = qa;
    *(uint4*)&PcatH[bn*64 + 32 + og*4] = pa;
}

// ---------------------------------------------------------------------------
// Kernel 2: fused main + f-layer, software-pipelined.
//  R5 structure (coalesced uniform-row gathers, LDS fuse, 2 barriers/round)
//  but: all 8 rounds' idx rows preloaded; Pcat/Qs for round r+1 loaded into
//  registers BEFORE round r's barrier+MFMA -> gather latency overlapped.
// ---------------------------------------------------------------------------
__global__ __launch_bounds__(256) void k_main(
    const int*      __restrict__ idx,
    const uint_t*   __restrict__ QsH,
    const uint_t*   __restrict__ PcatH,
    const _Float16* __restrict__ Bpack,
    const float*    __restrict__ b_h,
    const float*    __restrict__ W_f,
    const float*    __restrict__ s_f, const float* __restrict__ b_f,
    const float*    __restrict__ features,
    float* __restrict__ outF)
{
    const int t    = threadIdx.x;
    const int w    = t >> 6;
    const int lane = t & 63;
    const int m    = lane & 31;
    const int hh   = lane >> 5;
    const int slot = w >> 1;     // MFMA-phase point slot
    const int oh   = w & 1;      // MFMA-phase o-half

    __shared__ uint_t fuse[2 * 32 * 66];               // [slot][row][word]
    __shared__ __align__(16) float pooledAll[PPB * 132];

    half8 Bf[2][8];
#pragma unroll
    for (int ob = 0; ob < 2; ob++)
#pragma unroll
        for (int c = 0; c < 8; c++)
            Bf[ob][c] = *(const half8*)&Bpack[(((oh*2 + ob)*8 + c)*64 + lane)*8];

    const float bh0 = b_h[(oh*2+0)*32 + m];
    const float bh1 = b_h[(oh*2+1)*32 + m];

    const int bnb   = blockIdx.x * PPB;
    const int base0 = bnb & ~(N_ - 1);                 // b*N_
    const half2v zero2 = {(_Float16)0.f, (_Float16)0.f};

    // preload all rounds' idx rows (lane-half hh -> point bn0+hh, neighbor m)
    int jallv[PPB/2];
#pragma unroll
    for (int r = 0; r < PPB/2; r++)
        jallv[r] = idx[((bnb + r*2 + hh) & (N_-1))*K_ + m];

    // prefetch round 0: Qs words + 16 coalesced Pcat row-gathers
    uint_t qw0 = QsH[(bnb+0)*64 + lane];
    uint_t qw1 = QsH[(bnb+1)*64 + lane];
    uint_t pg[16];
#pragma unroll
    for (int it = 0; it < 16; it++) {
        const int rs = it*4 + w;
        const int j  = __shfl(jallv[0], rs);           // uniform -> readlane
        pg[it] = PcatH[(size_t)(base0 + j)*64 + lane];
    }

#pragma unroll
    for (int rr = 0; rr < PPB/2; rr++) {
        // ---- write fuse for round rr from registers ----
#pragma unroll
        for (int it = 0; it < 16; it++) {
            const int rs  = it*4 + w;
            const int sl  = rs >> 5, row = rs & 31;
            HU a, p; a.u = sl ? qw1 : qw0; p.u = pg[it];
            half2v v = a.h + p.h;                      // v_pk_add_f16
            v = __builtin_elementwise_max(v, zero2);   // v_pk_max_f16
            HU o2; o2.h = v;
            fuse[sl*2112 + row*66 + lane] = o2.u;
        }
        // ---- prefetch round rr+1 (overlaps barrier + MFMA below) ----
        if (rr + 1 < PPB/2) {
            const int bn0n = bnb + (rr+1)*2;
            qw0 = QsH[(bn0n+0)*64 + lane];
            qw1 = QsH[(bn0n+1)*64 + lane];
#pragma unroll
            for (int it = 0; it < 16; it++) {
                const int rs = it*4 + w;
                const int j  = __shfl(jallv[rr+1], rs);
                pg[it] = PcatH[(size_t)(base0 + j)*64 + lane];
            }
        }
        __syncthreads();

        // ---- MFMA phase on this round's fuse ----
        floatx16 acc0 = {}, acc1 = {};
#pragma unroll
        for (int c = 0; c < 8; c++) {
            const int wb = slot*2112 + m*66 + c*8 + hh*4;
            union { uint_t u[4]; half8 h; } av;
            *(uint2*)&av.u[0] = *(const uint2*)&fuse[wb];
            *(uint2*)&av.u[2] = *(const uint2*)&fuse[wb + 2];
            acc0 = __builtin_amdgcn_mfma_f32_32x32x16_f16(av.h, Bf[0][c], acc0, 0, 0, 0);
            acc1 = __builtin_amdgcn_mfma_f32_32x32x16_f16(av.h, Bf[1][c], acc1, 0, 0, 0);
        }

        float v0 = 0.f, v1 = 0.f;
#pragma unroll
        for (int rg = 0; rg < 16; rg++) {
            v0 += fmaxf(acc0[rg] + bh0, 0.f);
            v1 += fmaxf(acc1[rg] + bh1, 0.f);
        }
        v0 += __shfl_xor(v0, 32);
        v1 += __shfl_xor(v1, 32);
        const int nl = rr*2 + slot;
        if (hh == 0) {
            pooledAll[nl*132 + (oh*2+0)*32 + m] = v0;
            pooledAll[nl*132 + (oh*2+1)*32 + m] = v1;
        }
        __syncthreads();   // fuse fully consumed before next round's writes
    }

    // ---- f layer + residual for the block's 16 points ----
    const int b  = bnb >> 12;
    const int n0 = bnb & (N_ - 1);
    const int c  = t >> 2;       // 0..63
    const int nq = t & 3;        // 4 n's per thread

    float acc[4] = {};
    for (int i0 = 0; i0 < DH_; i0 += 4) {
        const float4 wv = *(const float4*)&W_f[c*DH_ + i0];
#pragma unroll
        for (int r = 0; r < 4; r++) {
            const float4 p = *(const float4*)&pooledAll[(nq*4 + r)*132 + i0];
            acc[r] += wv.x*p.x + wv.y*p.y + wv.z*p.z + wv.w*p.w;
        }
    }
    const float sfc = s_f[c] * (1.f/(float)K_);
    const float bfc = b_f[c];
    const float4 fr = *(const float4*)&features[(b*C_ + c)*N_ + n0 + nq*4];
    float4 ov;
    ov.x = fmaxf(acc[0]*sfc + bfc, 0.f) + fr.x;
    ov.y = fmaxf(acc[1]*sfc + bfc, 0.f) + fr.y;
    ov.z = fmaxf(acc[2]*sfc + bfc, 0.f) + fr.z;
    ov.w = fmaxf(acc[3]*sfc + bfc, 0.f) + fr.w;
    *(float4*)&outF[(b*C_ + c)*N_ + n0 + nq*4] = ov;
}

// ---------------------------------------------------------------------------
extern "C" void kernel_launch(void* const* d_in, const int* in_sizes, int n_in,
                              void* d_out, int out_size, void* d_ws, size_t ws_size,
                              hipStream_t stream)
{
    const float* xyz      = (const float*)d_in[0];
    const float* features = (const float*)d_in[1];
    const int*   idx      = (const int*)  d_in[2];
    const float* W_gu     = (const float*)d_in[3];
    const float* s_gu     = (const float*)d_in[4];
    const float* b_gu     = (const float*)d_in[5];
    const float* W_gv     = (const float*)d_in[6];
    const float* s_gv     = (const float*)d_in[7];
    const float* b_gv     = (const float*)d_in[8];
    const float* W_h      = (const float*)d_in[9];
    const float* s_h      = (const float*)d_in[10];
    const float* b_h      = (const float*)d_in[11];
    const float* W_f      = (const float*)d_in[12];
    const float* s_f      = (const float*)d_in[13];
    const float* b_f      = (const float*)d_in[14];

    float* out  = (float*)d_out;          // tuple: xyz first, then out
    float* outF = out + B_*N_*3;

    // workspace carve (~8.1 MB)
    char* wp = (char*)d_ws;
    uint_t*   QsH   = (uint_t*)wp;   wp += (size_t)B_*N_*64*4;    // 4 MB
    uint_t*   PcatH = (uint_t*)wp;   wp += (size_t)B_*N_*64*4;    // 4 MB
    _Float16* Bpack = (_Float16*)wp; wp += DH_*DH_*2;             // 32 KB

    k_prep<<<B_*(N_/32), 256, 0, stream>>>(xyz, features, W_gv, W_gu,
                                           s_gu, b_gu, s_gv, b_gv, W_h, s_h,
                                           out, Bpack, QsH, PcatH);
    k_main<<<(B_*N_)/PPB, 256, 0, stream>>>(idx, QsH, PcatH, Bpack, b_h,
                                            W_f, s_f, b_f, features, outF);
}

// Round 8
// 130.286 us; speedup vs baseline: 1.1546x; 1.0012x over previous
//
#include <hip/hip_runtime.h>

#define B_  4
#define N_  4096
#define K_  32
#define C_  64
#define DH_ 128
#define PPB 8

typedef _Float16 half2v __attribute__((ext_vector_type(2)));
typedef _Float16 half8  __attribute__((ext_vector_type(8)));
typedef __fp16   fp16x2 __attribute__((ext_vector_type(2)));
typedef float  floatx16 __attribute__((ext_vector_type(16)));
typedef unsigned int uint_t;

union HU { half2v h; uint_t u; };
union HU2 { fp16x2 h; uint_t u; };

__device__ __forceinline__ uint_t pk2(float a, float b) {
    HU2 x; x.h = __builtin_amdgcn_cvt_pkrtz(a, b);   // v_cvt_pkrtz_f16_f32
    return x.u;
}

// ---------------------------------------------------------------------------
// Kernel 1 (merged prep): 512 blocks x 256 thr; block = (b = blk>>7, 32-pt tile).
//  UNCHANGED from R7 (frozen to isolate the k_main experiment).
// ---------------------------------------------------------------------------
__global__ __launch_bounds__(256) void k_prep(
    const float* __restrict__ xyz,
    const float* __restrict__ features,
    const float* __restrict__ W_gv,
    const float* __restrict__ W_gu,
    const float* __restrict__ s_gu, const float* __restrict__ b_gu,
    const float* __restrict__ s_gv, const float* __restrict__ b_gv,
    const float* __restrict__ W_h,  const float* __restrict__ s_h,
    float* __restrict__ out_xyz,
    _Float16* __restrict__ Bpack,
    uint_t* __restrict__ QsH,
    uint_t* __restrict__ PcatH)
{
    const int blk = blockIdx.x;
    const int b   = blk >> 7;
    const int n0  = (blk & 127) * 32;
    const int t   = threadIdx.x;

    // side job A: xyz copy (output 0 of the tuple). 512*96 = 49152.
    if (t < 96) { int e = blk*96 + t; out_xyz[e] = xyz[e]; }
    // side job B: Bpack = (W_h * s_h) f16, MFMA B-frag order. 512*32 = 16384.
    {
        int e = blk*32 + t;
        if (t < 32) {
            int j = e & 7, l = (e >> 3) & 63, c = (e >> 9) & 7, ob = e >> 12;
            int o = ob*32 + (l & 31);
            int i = c*16 + (l >> 5)*8 + j;
            Bpack[e] = (_Float16)(W_h[o*DH_ + i] * s_h[o]);
        }
    }

    __shared__ __align__(16) float ftile[64 * 33];   // [c][n], stride 33
    __shared__ __align__(16) float wtile[64 * 68];   // [c][o], stride 68

#pragma unroll
    for (int r = 0; r < 2; r++) {    // features tile: 64c x 32n
        const int i4 = r*256 + t, c = i4 >> 3, nq = i4 & 7;
        const float4 f4 = *(const float4*)&features[(b*C_ + c)*N_ + n0 + nq*4];
        ftile[c*33 + nq*4 + 0] = f4.x;
        ftile[c*33 + nq*4 + 1] = f4.y;
        ftile[c*33 + nq*4 + 2] = f4.z;
        ftile[c*33 + nq*4 + 3] = f4.w;
    }
#pragma unroll
    for (int r = 0; r < 4; r++) {    // W_gv transposed: [c][o]
        const int e4 = r*256 + t, o = e4 >> 4, c0 = (e4 & 15)*4;
        const float4 w4 = *(const float4*)&W_gv[o*C_ + c0];
        wtile[(c0+0)*68 + o] = w4.x;
        wtile[(c0+1)*68 + o] = w4.y;
        wtile[(c0+2)*68 + o] = w4.z;
        wtile[(c0+3)*68 + o] = w4.w;
    }
    __syncthreads();

    const int n  = t >> 3;       // 0..31
    const int og = t & 7;        // o-chunk of 8
    const int o0 = og * 8;

    float acc[8] = {};
    for (int c = 0; c < 64; c++) {
        const float a = ftile[c*33 + n];            // 8-lane broadcast
        float wv[8];
        *(float4*)&wv[0] = *(const float4*)&wtile[c*68 + o0];
        *(float4*)&wv[4] = *(const float4*)&wtile[c*68 + o0 + 4];
#pragma unroll
        for (int oo = 0; oo < 8; oo++)
            acc[oo] = fmaf(a, wv[oo], acc[oo]);
    }

    const int bn = b*N_ + n0 + n;
    const float x0 = xyz[bn*3+0], x1 = xyz[bn*3+1], x2 = xyz[bn*3+2];

    float sgu[8], bgu[8], sgv[8], bgv[8];
    *(float4*)&sgu[0] = *(const float4*)&s_gu[o0]; *(float4*)&sgu[4] = *(const float4*)&s_gu[o0+4];
    *(float4*)&bgu[0] = *(const float4*)&b_gu[o0]; *(float4*)&bgu[4] = *(const float4*)&b_gu[o0+4];
    *(float4*)&sgv[0] = *(const float4*)&s_gv[o0]; *(float4*)&sgv[4] = *(const float4*)&s_gv[o0+4];
    *(float4*)&bgv[0] = *(const float4*)&b_gv[o0]; *(float4*)&bgv[4] = *(const float4*)&b_gv[o0+4];

    float qv[8], rv[8];
#pragma unroll
    for (int oo = 0; oo < 8; oo++) {
        const int o = o0 + oo;
        qv[oo] = x0*W_gu[o*6+0] + x1*W_gu[o*6+1] + x2*W_gu[o*6+2];
        rv[oo] = x0*W_gu[o*6+3] + x1*W_gu[o*6+4] + x2*W_gu[o*6+5];
    }
    uint4 qa, pa;
    // gu half (words 0..31)
    qa.x = pk2(qv[0]*sgu[0]+bgu[0], qv[1]*sgu[1]+bgu[1]);
    qa.y = pk2(qv[2]*sgu[2]+bgu[2], qv[3]*sgu[3]+bgu[3]);
    qa.z = pk2(qv[4]*sgu[4]+bgu[4], qv[5]*sgu[5]+bgu[5]);
    qa.w = pk2(qv[6]*sgu[6]+bgu[6], qv[7]*sgu[7]+bgu[7]);
    pa.x = pk2(rv[0]*sgu[0], rv[1]*sgu[1]);
    pa.y = pk2(rv[2]*sgu[2], rv[3]*sgu[3]);
    pa.z = pk2(rv[4]*sgu[4], rv[5]*sgu[5]);
    pa.w = pk2(rv[6]*sgu[6], rv[7]*sgu[7]);
    *(uint4*)&QsH  [bn*64 + og*4] = qa;
    *(uint4*)&PcatH[bn*64 + og*4] = pa;
    // gv half (words 32..63)
    qa.x = pk2(acc[0]*sgv[0]+bgv[0], acc[1]*sgv[1]+bgv[1]);
    qa.y = pk2(acc[2]*sgv[2]+bgv[2], acc[3]*sgv[3]+bgv[3]);
    qa.z = pk2(acc[4]*sgv[4]+bgv[4], acc[5]*sgv[5]+bgv[5]);
    qa.w = pk2(acc[6]*sgv[6]+bgv[6], acc[7]*sgv[7]+bgv[7]);
    pa.x = pk2(acc[0]*sgv[0], acc[1]*sgv[1]);
    pa.y = pk2(acc[2]*sgv[2], acc[3]*sgv[3]);
    pa.z = pk2(acc[4]*sgv[4], acc[5]*sgv[5]);
    pa.w = pk2(acc[6]*sgv[6], acc[7]*sgv[7]);
    *(uint4*)&QsH  [bn*64 + 32 + og*4] = qa;
    *(uint4*)&PcatH[bn*64 + 32 + og*4] = pa;
}

// ---------------------------------------------------------------------------
// Kernel 2: fused main + f-layer, software-pipelined. PPB=8 -> 2048 blocks
// (8 blocks/CU queued, ~5 resident) for gather-latency hiding via TLP.
// ---------------------------------------------------------------------------
__global__ __launch_bounds__(256) void k_main(
    const int*      __restrict__ idx,
    const uint_t*   __restrict__ QsH,
    const uint_t*   __restrict__ PcatH,
    const _Float16* __restrict__ Bpack,
    const float*    __restrict__ b_h,
    const float*    __restrict__ W_f,
    const float*    __restrict__ s_f, const float* __restrict__ b_f,
    const float*    __restrict__ features,
    float* __restrict__ outF)
{
    const int t    = threadIdx.x;
    const int w    = t >> 6;
    const int lane = t & 63;
    const int m    = lane & 31;
    const int hh   = lane >> 5;
    const int slot = w >> 1;     // MFMA-phase point slot
    const int oh   = w & 1;      // MFMA-phase o-half

    __shared__ uint_t fuse[2 * 32 * 66];               // [slot][row][word]
    __shared__ __align__(16) float pooledAll[PPB * 132];

    half8 Bf[2][8];
#pragma unroll
    for (int ob = 0; ob < 2; ob++)
#pragma unroll
        for (int c = 0; c < 8; c++)
            Bf[ob][c] = *(const half8*)&Bpack[(((oh*2 + ob)*8 + c)*64 + lane)*8];

    const float bh0 = b_h[(oh*2+0)*32 + m];
    const float bh1 = b_h[(oh*2+1)*32 + m];

    const int bnb   = blockIdx.x * PPB;
    const int base0 = bnb & ~(N_ - 1);                 // b*N_
    const half2v zero2 = {(_Float16)0.f, (_Float16)0.f};

    // preload all rounds' idx rows (lane-half hh -> point bn0+hh, neighbor m)
    int jallv[PPB/2];
#pragma unroll
    for (int r = 0; r < PPB/2; r++)
        jallv[r] = idx[((bnb + r*2 + hh) & (N_-1))*K_ + m];

    // prefetch round 0: Qs words + 16 coalesced Pcat row-gathers
    uint_t qw0 = QsH[(bnb+0)*64 + lane];
    uint_t qw1 = QsH[(bnb+1)*64 + lane];
    uint_t pg[16];
#pragma unroll
    for (int it = 0; it < 16; it++) {
        const int rs = it*4 + w;
        const int j  = __shfl(jallv[0], rs);           // uniform -> readlane
        pg[it] = PcatH[(size_t)(base0 + j)*64 + lane];
    }

#pragma unroll
    for (int rr = 0; rr < PPB/2; rr++) {
        // ---- write fuse for round rr from registers ----
#pragma unroll
        for (int it = 0; it < 16; it++) {
            const int rs  = it*4 + w;
            const int sl  = rs >> 5, row = rs & 31;
            HU a, p; a.u = sl ? qw1 : qw0; p.u = pg[it];
            half2v v = a.h + p.h;                      // v_pk_add_f16
            v = __builtin_elementwise_max(v, zero2);   // v_pk_max_f16
            HU o2; o2.h = v;
            fuse[sl*2112 + row*66 + lane] = o2.u;
        }
        // ---- prefetch round rr+1 (overlaps barrier + MFMA below) ----
        if (rr + 1 < PPB/2) {
            const int bn0n = bnb + (rr+1)*2;
            qw0 = QsH[(bn0n+0)*64 + lane];
            qw1 = QsH[(bn0n+1)*64 + lane];
#pragma unroll
            for (int it = 0; it < 16; it++) {
                const int rs = it*4 + w;
                const int j  = __shfl(jallv[rr+1], rs);
                pg[it] = PcatH[(size_t)(base0 + j)*64 + lane];
            }
        }
        __syncthreads();

        // ---- MFMA phase on this round's fuse ----
        floatx16 acc0 = {}, acc1 = {};
#pragma unroll
        for (int c = 0; c < 8; c++) {
            const int wb = slot*2112 + m*66 + c*8 + hh*4;
            union { uint_t u[4]; half8 h; } av;
            *(uint2*)&av.u[0] = *(const uint2*)&fuse[wb];
            *(uint2*)&av.u[2] = *(const uint2*)&fuse[wb + 2];
            acc0 = __builtin_amdgcn_mfma_f32_32x32x16_f16(av.h, Bf[0][c], acc0, 0, 0, 0);
            acc1 = __builtin_amdgcn_mfma_f32_32x32x16_f16(av.h, Bf[1][c], acc1, 0, 0, 0);
        }

        float v0 = 0.f, v1 = 0.f;
#pragma unroll
        for (int rg = 0; rg < 16; rg++) {
            v0 += fmaxf(acc0[rg] + bh0, 0.f);
            v1 += fmaxf(acc1[rg] + bh1, 0.f);
        }
        v0 += __shfl_xor(v0, 32);
        v1 += __shfl_xor(v1, 32);
        const int nl = rr*2 + slot;
        if (hh == 0) {
            pooledAll[nl*132 + (oh*2+0)*32 + m] = v0;
            pooledAll[nl*132 + (oh*2+1)*32 + m] = v1;
        }
        __syncthreads();   // fuse fully consumed before next round's writes
    }

    // ---- f layer + residual for the block's 8 points ----
    const int b   = bnb >> 12;
    const int n0  = bnb & (N_ - 1);
    const int c   = t >> 2;      // 0..63
    const int sub = t & 3;       // 2 n's per thread

    float acc[2] = {};
    for (int i0 = 0; i0 < DH_; i0 += 4) {
        const float4 wv = *(const float4*)&W_f[c*DH_ + i0];
#pragma unroll
        for (int r = 0; r < 2; r++) {
            const float4 p = *(const float4*)&pooledAll[(sub*2 + r)*132 + i0];
            acc[r] += wv.x*p.x + wv.y*p.y + wv.z*p.z + wv.w*p.w;
        }
    }
    const float sfc = s_f[c] * (1.f/(float)K_);
    const float bfc = b_f[c];
    const float2 fr = *(const float2*)&features[(b*C_ + c)*N_ + n0 + sub*2];
    float2 ov;
    ov.x = fmaxf(acc[0]*sfc + bfc, 0.f) + fr.x;
    ov.y = fmaxf(acc[1]*sfc + bfc, 0.f) + fr.y;
    *(float2*)&outF[(b*C_ + c)*N_ + n0 + sub*2] = ov;
}

// ---------------------------------------------------------------------------
extern "C" void kernel_launch(void* const* d_in, const int* in_sizes, int n_in,
                              void* d_out, int out_size, void* d_ws, size_t ws_size,
                              hipStream_t stream)
{
    const float* xyz      = (const float*)d_in[0];
    const float* features = (const float*)d_in[1];
    const int*   idx      = (const int*)  d_in[2];
    const float* W_gu     = (const float*)d_in[3];
    const float* s_gu     = (const float*)d_in[4];
    const float* b_gu     = (const float*)d_in[5];
    const float* W_gv     = (const float*)d_in[6];
    const float* s_gv     = (const float*)d_in[7];
    const float* b_gv     = (const float*)d_in[8];
    const float* W_h      = (const float*)d_in[9];
    const float* s_h      = (const float*)d_in[10];
    const float* b_h      = (const float*)d_in[11];
    const float* W_f      = (const float*)d_in[12];
    const float* s_f      = (const float*)d_in[13];
    const float* b_f      = (const float*)d_in[14];

    float* out  = (float*)d_out;          // tuple: xyz first, then out
    float* outF = out + B_*N_*3;

    // workspace carve (~8.1 MB)
    char* wp = (char*)d_ws;
    uint_t*   QsH   = (uint_t*)wp;   wp += (size_t)B_*N_*64*4;    // 4 MB
    uint_t*   PcatH = (uint_t*)wp;   wp += (size_t)B_*N_*64*4;    // 4 MB
    _Float16* Bpack = (_Float16*)wp; wp += DH_*DH_*2;             // 32 KB

    k_prep<<<B_*(N_/32), 256, 0, stream>>>(xyz, features, W_gv, W_gu,
                                           s_gu, b_gu, s_gv, b_gv, W_h, s_h,
                                           out, Bpack, QsH, PcatH);
    k_main<<<(B_*N_)/PPB, 256, 0, stream>>>(idx, QsH, PcatH, Bpack, b_h,
                                            W_f, s_f, b_f, features, outF);
}